// Round 20
// baseline (369.863 us; speedup 1.0000x reference)
//
#include <hip/hip_runtime.h>
#include <math.h>

// ---------------- K1: conv1 (1ci->50co, 3x7 circular, 64x256) + maxpool 2x4 + relu ---
// grid (8 rowgrp, 5 cochunk, 32 img) x 256 thr. Weight transpose folded into y==0.
// Input window as 3 aligned float4 per row (12 coalesced loads/thread) - r13 verified.
// r20: w2 transpose now writes the k2-tiled layout [ci][coc(5)][tap(21)][co(10)] so
// each (ci, co-chunk) weight packet is 210 CONTIGUOUS floats (wide s_load batches).
__global__ __launch_bounds__(256) void k1(const float* __restrict__ x,
                                          const float* __restrict__ w1,
                                          const float* __restrict__ b1,
                                          float* __restrict__ a1,
                                          const float* __restrict__ w2,
                                          const float* __restrict__ w3,
                                          const float* __restrict__ w4,
                                          float* __restrict__ w2t,
                                          float* __restrict__ w3t,
                                          float* __restrict__ w4t) {
  int b = blockIdx.z;
  int pr0 = blockIdx.x * 4;
  int co0 = blockIdx.y * 10;
  int ty = threadIdx.x >> 6;       // 0..3
  int pc = threadIdx.x & 63;       // pooled col 0..63
  int pr = pr0 + ty;
  const float* xb = x + b * (64 * 256);
  float xw[4][12];                 // cols 4pc-8 .. 4pc+3
#pragma unroll
  for (int r = 0; r < 4; ++r) {
    int row = (2 * pr - 2 + r) & 63;
    const float* rb = xb + row * 256;
#pragma unroll
    for (int v = 0; v < 3; ++v) {
      int col = (4 * pc - 8 + 4 * v) & 255;      // 4-aligned, wraps cleanly
      float4 t = *(const float4*)&rb[col];
      xw[r][4 * v + 0] = t.x; xw[r][4 * v + 1] = t.y;
      xw[r][4 * v + 2] = t.z; xw[r][4 * v + 3] = t.w;
    }
  }
#pragma unroll
  for (int cq = 0; cq < 10; ++cq) {
    int co = co0 + cq;
    const float* wp = w1 + co * 21;      // wave-uniform -> scalar loads
    float m = -1e30f;
#pragma unroll
    for (int iy = 0; iy < 2; ++iy) {
#pragma unroll
      for (int jx = 0; jx < 4; ++jx) {
        float s = 0.f;
#pragma unroll
        for (int di = 0; di < 3; ++di)
#pragma unroll
          for (int dj = 0; dj < 7; ++dj)
            s = fmaf(xw[iy + 2 - di][jx + 8 - dj], wp[di * 7 + dj], s);
        m = fmaxf(m, s);
      }
    }
    float v = fmaxf(m + b1[co], 0.f);
    a1[((b * 50 + co) * 32 + pr) * 64 + pc] = v;
  }
  // folded weight transpose.
  // w2t: [ci][coc(5)][tap(21)][co(10)]  (i = ((ci*5+coc)*21+tap)*10+co)
  // w3t/w4t: old [ci][tap][co(50)] layout.
  if (blockIdx.y == 0) {
    int base = (blockIdx.z * 8 + blockIdx.x) * 256 + threadIdx.x;  // 0..65535
    for (int i = base; i < 90000; i += 65536) {
      if (i < 52500) {
        // new tiled w2 transpose
        int co = i % 10; int t = i / 10;
        int tap = t % 21; t /= 21;
        int coc = t % 5;  int ci = t / 5;
        w2t[i] = w2[(coc * 10 + co) * 1050 + ci * 21 + tap];
        // w4 keeps old layout
        int co4 = i % 50, r4 = i / 50;
        w4t[i] = w4[co4 * 1050 + r4];
      } else {                  // w3: 50*50*3*5
        int j2 = i - 52500;
        int co = j2 % 50, r = j2 / 50;
        w3t[j2] = w3[co * 750 + r];
      }
    }
  }
}

// ---------------- K2: conv2 (50->50, 3x7 circular, 32x64) + maxpool 2x4 + relu -------
// r15 zero-barrier form (94 us verified) with r20 weight-packet layout: per (ci,coc)
// the 210 weight floats are contiguous -> compiler emits wide s_load_dwordx16 batches,
// scalar stream near-sequential (7 cache lines/ci vs 21+ scattered). Structure, FMA
// order, and grid identical to the frozen form.
__global__ __launch_bounds__(256) void k2(const float* __restrict__ a1,
                                          const float* __restrict__ w2t,
                                          const float* __restrict__ b2,
                                          float* __restrict__ a2) {
  __shared__ float sm[2560];       // pool epilogue only: [co(10)][row(4)][col(64)]
  int b = blockIdx.z;
  int r0 = blockIdx.x * 4;         // pre-pool rows r0..r0+3
  int cocB = blockIdx.y;           // co chunk (10 co): packs two 5-co tiles coc=2*cocB,+1
  int co0 = cocB * 10;
  int y = threadIdx.x >> 6;        // 0..3 (wave id) -> pre-pool row r0+y
  int lane = threadIdx.x & 63;     // column
  int offA = ((r0 + y - 2) & 31) * 64 + lane;
  int offB = ((r0 + y - 1) & 31) * 64 + lane;
  int offC = ((r0 + y) & 31) * 64 + lane;
  int idx1 = (lane - 1) & 63, idx2 = (lane - 2) & 63, idx3 = (lane - 3) & 63;
  int idx4 = (lane - 4) & 63, idx5 = (lane - 5) & 63, idx6 = (lane - 6) & 63;
  float acc[10];
#pragma unroll
  for (int co = 0; co < 10; ++co) acc[co] = b2[co0 + co];
  const float* ain = a1 + b * (50 * 2048);
  float vA = ain[offA], vB = ain[offB], vC = ain[offC];
  for (int ci = 0; ci < 50; ++ci) {
    int cin = (ci + 1 < 50) ? (ci + 1) : 49;
    const float* np = ain + cin * 2048;
    float nA = np[offA], nB = np[offB], nC = np[offC];
    // two contiguous 210-float packets: coc = 2*cocB (co 0..4), 2*cocB+1 (co 5..9)
    const float* wpk0 = w2t + (ci * 5 + 2 * cocB) * 210;       // wave-uniform
    const float* wpk1 = wpk0 + 210;
#pragma unroll
    for (int di = 0; di < 3; ++di) {
      float v = (di == 0) ? vC : (di == 1) ? vB : vA;
      const float* wr0 = wpk0 + di * 70;     // [tap7][co10] slice, contiguous
      const float* wr1 = wpk1 + di * 70;
      float x1 = __shfl(v, idx1, 64);
      float x2 = __shfl(v, idx2, 64);
      float x3 = __shfl(v, idx3, 64);
      float x4 = __shfl(v, idx4, 64);
      float x5 = __shfl(v, idx5, 64);
      float x6 = __shfl(v, idx6, 64);
#pragma unroll
      for (int co = 0; co < 5; ++co) acc[co] = fmaf(v,  wr0[co], acc[co]);
#pragma unroll
      for (int co = 0; co < 5; ++co) acc[5 + co] = fmaf(v,  wr1[co], acc[5 + co]);
#pragma unroll
      for (int co = 0; co < 5; ++co) acc[co] = fmaf(x1, wr0[10 + co], acc[co]);
#pragma unroll
      for (int co = 0; co < 5; ++co) acc[5 + co] = fmaf(x1, wr1[10 + co], acc[5 + co]);
#pragma unroll
      for (int co = 0; co < 5; ++co) acc[co] = fmaf(x2, wr0[20 + co], acc[co]);
#pragma unroll
      for (int co = 0; co < 5; ++co) acc[5 + co] = fmaf(x2, wr1[20 + co], acc[5 + co]);
#pragma unroll
      for (int co = 0; co < 5; ++co) acc[co] = fmaf(x3, wr0[30 + co], acc[co]);
#pragma unroll
      for (int co = 0; co < 5; ++co) acc[5 + co] = fmaf(x3, wr1[30 + co], acc[5 + co]);
#pragma unroll
      for (int co = 0; co < 5; ++co) acc[co] = fmaf(x4, wr0[40 + co], acc[co]);
#pragma unroll
      for (int co = 0; co < 5; ++co) acc[5 + co] = fmaf(x4, wr1[40 + co], acc[5 + co]);
#pragma unroll
      for (int co = 0; co < 5; ++co) acc[co] = fmaf(x5, wr0[50 + co], acc[co]);
#pragma unroll
      for (int co = 0; co < 5; ++co) acc[5 + co] = fmaf(x5, wr1[50 + co], acc[5 + co]);
#pragma unroll
      for (int co = 0; co < 5; ++co) acc[co] = fmaf(x6, wr0[60 + co], acc[co]);
#pragma unroll
      for (int co = 0; co < 5; ++co) acc[5 + co] = fmaf(x6, wr1[60 + co], acc[5 + co]);
    }
    vA = nA; vB = nB; vC = nC;
  }
  // pool 2x4 + relu through LDS (conflict-free)
#pragma unroll
  for (int k = 0; k < 10; ++k)
    sm[k * 256 + y * 64 + lane] = acc[k];
  __syncthreads();
  for (int w = threadIdx.x; w < 320; w += 256) {
    int cop = w / 32;
    int pr = (w >> 4) & 1;
    int pc = w & 15;
    float m = -1e30f;
#pragma unroll
    for (int yy = 0; yy < 2; ++yy)
#pragma unroll
      for (int xx = 0; xx < 4; ++xx)
        m = fmaxf(m, sm[cop * 256 + (pr * 2 + yy) * 64 + pc * 4 + xx]);
    m = fmaxf(m, 0.f);
    a2[((b * 50 + co0 + cop) * 16 + (r0 >> 1) + pr) * 16 + pc] = m;
  }
}

// ---------------- K3: combine(even + mean(odd)) -> upsample(2,4)-sparse conv3 (3x5) + relu
// r14 verified: co-chunk 5, grid (4,10,16)=640 blocks. r18: mean phase vectorized.
__global__ __launch_bounds__(512) void k3(const float* __restrict__ a2,
                                          const float* __restrict__ w3t,
                                          const float* __restrict__ b3,
                                          float* __restrict__ a3) {
  __shared__ float ts[4000];     // [ci(50)][rr(5)][tc(16)]
  __shared__ float mean_s[64];
  __shared__ float part[200];
  int b = blockIdx.z;
  int r0 = blockIdx.x * 8;       // output rows r0..r0+7
  int co0 = blockIdx.y * 5;      // co chunk of 5
  int tid = threadIdx.x;
  const float* aodd = a2 + (2 * b + 1) * (50 * 256);
  if (tid < 200) {
    int ci = tid >> 2, p = tid & 3;
    const float4* ap = (const float4*)(aodd + ci * 256 + p * 64);
    float s = 0.f;
#pragma unroll
    for (int k = 0; k < 16; ++k) {
      float4 t = ap[k];
      s += t.x; s += t.y; s += t.z; s += t.w;
    }
    part[tid] = s;
  }
  __syncthreads();
  if (tid < 50)
    mean_s[tid] = (part[4 * tid] + part[4 * tid + 1] + part[4 * tid + 2] + part[4 * tid + 3]) * (1.f / 256.f);
  __syncthreads();
  const float* aev = a2 + (2 * b) * (50 * 256);
  for (int e = tid; e < 4000; e += 512) {
    int ci = e / 80;
    int rr = (e >> 4) % 5;
    int tc = e & 15;
    int trow = ((r0 >> 1) - 1 + rr) & 15;
    ts[e] = aev[ci * 256 + trow * 16 + tc] + mean_s[ci];
  }
  __syncthreads();
  int wv = __builtin_amdgcn_readfirstlane(tid >> 6);   // 0..7, force SGPR
  int lane = tid & 63;
  int p = wv >> 2;               // row parity class
  int m = wv & 3;                // j%4 class
  int q = lane & 15;
  int yidx = lane >> 4;          // 0..3
  int i = r0 + 2 * yidx + p;
  int j = 4 * q + m;
  float acc[5];
#pragma unroll
  for (int co = 0; co < 5; ++co) acc[co] = b3[co0 + co];
  int ndi = (p == 0) ? 2 : 1;    // even rows: di in {0,2}; odd: {1}
  int ndj = (m == 0) ? 2 : 1;    // kw=5: m==0 -> dj in {0,4}; else {m}
  for (int aa = 0; aa < ndi; ++aa) {
    int di = (p == 0) ? (2 * aa) : 1;
    int rr = 1 + ((2 * yidx + p - di) >> 1);
    for (int e2 = 0; e2 < ndj; ++e2) {
      int dj = (m == 0) ? (4 * e2) : m;
      int tc = ((j - dj + 64) >> 2) & 15;
      for (int ci = 0; ci < 50; ++ci) {
        float xv = ts[ci * 80 + rr * 16 + tc];
        const float* wrow = w3t + (ci * 15 + di * 5 + dj) * 50 + co0;  // wave-uniform
#pragma unroll
        for (int co = 0; co < 5; ++co)
          acc[co] = fmaf(xv, wrow[co], acc[co]);
      }
    }
  }
  float* aout = a3 + b * (50 * 2048);
#pragma unroll
  for (int co = 0; co < 5; ++co)
    aout[(co0 + co) * 2048 + i * 64 + j] = fmaxf(acc[co], 0.f);
}

// ---------------- K4: upsample(2,4)-sparse conv4 (3x7, 64x256) + relu ----------------
// r10-verified LDS ratio-2 form. Rows r0+rowsel and r0+rowsel+2.
// grid (16,5,16)=1280 x 512 thr.
__global__ __launch_bounds__(512) void k4(const float* __restrict__ a3,
                                          const float* __restrict__ w4t,
                                          const float* __restrict__ b4,
                                          float* __restrict__ a4) {
  __shared__ __align__(16) float s4[9600];   // [ci(50)][rr(3)][col(64)]
  int b = blockIdx.z;
  int r0 = blockIdx.x * 4;       // output rows r0..r0+3
  int co0 = blockIdx.y * 10;
  int tid = threadIdx.x;
  const float* ain = a3 + b * (50 * 2048);
  int prb = (r0 >> 1) - 1;       // pooled-row base (rr=0)
  for (int e = tid; e < 2400; e += 512) {    // float4 granules [ci][rr(3)][c4(16)]
    int ci = e / 48;
    int rem = e - ci * 48;
    int rr = rem >> 4;
    int c4 = rem & 15;
    int row = (prb + rr) & 31;
    *(float4*)&s4[(ci * 3 + rr) * 64 + c4 * 4] =
        *(const float4*)&ain[ci * 2048 + row * 64 + c4 * 4];
  }
  __syncthreads();
  int wv = __builtin_amdgcn_readfirstlane(tid >> 6);  // 0..7
  int lane = tid & 63;
  int rowsel = wv >> 2;          // 0..1 (wave-uniform)
  int m = wv & 3;
  int j = 4 * lane + m;
  float acc[2][10];
#pragma unroll
  for (int co = 0; co < 10; ++co) {
    float bc = b4[co0 + co];
    acc[0][co] = bc; acc[1][co] = bc;
  }
  int ndi = (rowsel == 0) ? 2 : 1;
  int ndj = (m < 3) ? 2 : 1;     // kw=7: dj in {m, m+4} when m<3
  for (int aa = 0; aa < ndi; ++aa) {
    int di = (rowsel == 0) ? (2 * aa) : 1;
    int rrb = 1 + ((rowsel - di) >> 1);   // rr for the k=0 row; k=1 row uses rrb+1
    for (int e2 = 0; e2 < ndj; ++e2) {
      int dj = m + 4 * e2;
      int tc = ((j - dj) >> 2) & 63;      // j-dj is multiple of 4
      for (int ci = 0; ci < 50; ++ci) {
        float xv0 = s4[ci * 192 + rrb * 64 + tc];
        float xv1 = s4[ci * 192 + (rrb + 1) * 64 + tc];
        const float* wrow = w4t + (ci * 21 + di * 7 + dj) * 50 + co0;  // wave-uniform
#pragma unroll
        for (int co = 0; co < 10; ++co) {
          float w = wrow[co];
          acc[0][co] = fmaf(xv0, w, acc[0][co]);
          acc[1][co] = fmaf(xv1, w, acc[1][co]);
        }
      }
    }
  }
  float* aout = a4 + b * (50 * 16384);
  int i0 = r0 + rowsel, i1 = r0 + rowsel + 2;
#pragma unroll
  for (int co = 0; co < 10; ++co) {
    aout[(co0 + co) * 16384 + i0 * 256 + j] = fmaxf(acc[0][co], 0.f);
    aout[(co0 + co) * 16384 + i1 * 256 + j] = fmaxf(acc[1][co], 0.f);
  }
}

// ---------------- K5: conv5 (50->1, 3x7 circular, 64x256) + sigmoid ------------------
// r18-verified: 8-row blocks (512 thr), 512 blocks; float4 staging; w5 in LDS;
// 10 ci-chunks of 5 (r19's chunk merge was neutral-negative -> reverted).
__global__ __launch_bounds__(512) void k5(const float* __restrict__ a4,
                                          const float* __restrict__ w5,
                                          const float* __restrict__ b5,
                                          float* __restrict__ out) {
  __shared__ __align__(16) float s5[4000];   // [ci(5)][rr(10)][c(80)], c-8 = col - jb
  __shared__ float smw5[1056];
  int bid = blockIdx.x;          // 512 blocks
  int b = bid >> 5;              // img 0..15
  int rem = bid & 31;
  int r0 = (rem >> 2) * 8;       // output rows r0..r0+7
  int jb = (rem & 3) * 64;       // col quarter base
  int tid = threadIdx.x;
  int y = tid >> 6;              // row 0..7
  int q = tid & 63;              // col within quarter
  for (int e = tid; e < 1050; e += 512) smw5[e] = w5[e];
  float acc = b5[0];
  const float* ain = a4 + b * (50 * 16384);
  for (int cc = 0; cc < 10; ++cc) {          // ci chunks of 5
    __syncthreads();
    for (int e = tid; e < 1000; e += 512) {  // float4 granules [ci(5)][rr(10)][g(20)]
      int ci = e / 200;
      int rem2 = e - ci * 200;
      int rr = rem2 / 20;
      int g = rem2 - rr * 20;
      int row = (r0 - 2 + rr) & 63;
      int col = (jb + 4 * g - 8) & 255;      // 4-aligned, wraps cleanly
      *(float4*)&s5[(ci * 10 + rr) * 80 + 4 * g] =
          *(const float4*)&ain[(cc * 5 + ci) * 16384 + row * 256 + col];
    }
    __syncthreads();
#pragma unroll
    for (int ci = 0; ci < 5; ++ci) {
#pragma unroll
      for (int di = 0; di < 3; ++di) {
        const float* base = s5 + ci * 800 + (y + 2 - di) * 80 + 8 + q;
        const float* wp = smw5 + ((cc * 5 + ci) * 3 + di) * 7;   // uniform LDS
#pragma unroll
        for (int dj = 0; dj < 7; ++dj)
          acc = fmaf(base[-dj], wp[dj], acc);
      }
    }
  }
  out[b * 16384 + (r0 + y) * 256 + jb + q] = 1.f / (1.f + expf(-acc));
}

extern "C" void kernel_launch(void* const* d_in, const int* in_sizes, int n_in,
                              void* d_out, int out_size, void* d_ws, size_t ws_size,
                              hipStream_t stream) {
  (void)in_sizes; (void)n_in; (void)out_size; (void)ws_size;
  const float* x  = (const float*)d_in[0];
  const float* w1 = (const float*)d_in[1];
  const float* b1 = (const float*)d_in[2];
  const float* w2 = (const float*)d_in[3];
  const float* b2 = (const float*)d_in[4];
  const float* w3 = (const float*)d_in[5];
  const float* b3 = (const float*)d_in[6];
  const float* w4 = (const float*)d_in[7];
  const float* b4 = (const float*)d_in[8];
  const float* w5 = (const float*)d_in[9];
  const float* b5 = (const float*)d_in[10];
  float* out = (float*)d_out;
  float* ws  = (float*)d_ws;
  float* w2t = ws;                       // 52500 (k2-tiled layout)
  float* w3t = w2t + 52500;              // 37500
  float* w4t = w3t + 37500;              // 52500
  float* a1  = w4t + 52500;              // 32*50*32*64  = 3,276,800
  float* a2  = a1 + 32 * 50 * 32 * 64;   // 32*50*16*16  = 409,600
  float* a3  = a2 + 32 * 50 * 16 * 16;   // 16*50*32*64  = 1,638,400
  float* a4  = a3 + 16 * 50 * 32 * 64;   // 16*50*64*256 = 13,107,200
  hipLaunchKernelGGL(k1, dim3(8, 5, 32), dim3(256), 0, stream, x, w1, b1, a1,
                     w2, w3, w4, w2t, w3t, w4t);
  hipLaunchKernelGGL(k2, dim3(8, 5, 32), dim3(256), 0, stream, a1, w2t, b2, a2);
  hipLaunchKernelGGL(k3, dim3(4, 10, 16), dim3(512), 0, stream, a2, w3t, b3, a3);
  hipLaunchKernelGGL(k4, dim3(16, 5, 16), dim3(512), 0, stream, a3, w4t, b4, a4);
  hipLaunchKernelGGL(k5, dim3(512), dim3(512), 0, stream, a4, w5, b5, out);
}

// Round 21
// 301.138 us; speedup vs baseline: 1.2282x; 1.2282x over previous
//
#include <hip/hip_runtime.h>
#include <math.h>

// ---------------- K1: conv1 (1ci->50co, 3x7 circular, 64x256) + maxpool 2x4 + relu ---
// grid (8 rowgrp, 5 cochunk, 32 img) x 256 thr. Weight transpose folded into y==0.
// w2t layout: [ci][coc(5)][tap(21)][co(10)] -> per (ci,coc) packet = 210 contiguous.
__global__ __launch_bounds__(256) void k1(const float* __restrict__ x,
                                          const float* __restrict__ w1,
                                          const float* __restrict__ b1,
                                          float* __restrict__ a1,
                                          const float* __restrict__ w2,
                                          const float* __restrict__ w3,
                                          const float* __restrict__ w4,
                                          float* __restrict__ w2t,
                                          float* __restrict__ w3t,
                                          float* __restrict__ w4t) {
  int b = blockIdx.z;
  int pr0 = blockIdx.x * 4;
  int co0 = blockIdx.y * 10;
  int ty = threadIdx.x >> 6;       // 0..3
  int pc = threadIdx.x & 63;       // pooled col 0..63
  int pr = pr0 + ty;
  const float* xb = x + b * (64 * 256);
  float xw[4][12];                 // cols 4pc-8 .. 4pc+3
#pragma unroll
  for (int r = 0; r < 4; ++r) {
    int row = (2 * pr - 2 + r) & 63;
    const float* rb = xb + row * 256;
#pragma unroll
    for (int v = 0; v < 3; ++v) {
      int col = (4 * pc - 8 + 4 * v) & 255;      // 4-aligned, wraps cleanly
      float4 t = *(const float4*)&rb[col];
      xw[r][4 * v + 0] = t.x; xw[r][4 * v + 1] = t.y;
      xw[r][4 * v + 2] = t.z; xw[r][4 * v + 3] = t.w;
    }
  }
#pragma unroll
  for (int cq = 0; cq < 10; ++cq) {
    int co = co0 + cq;
    const float* wp = w1 + co * 21;      // wave-uniform -> scalar loads
    float m = -1e30f;
#pragma unroll
    for (int iy = 0; iy < 2; ++iy) {
#pragma unroll
      for (int jx = 0; jx < 4; ++jx) {
        float s = 0.f;
#pragma unroll
        for (int di = 0; di < 3; ++di)
#pragma unroll
          for (int dj = 0; dj < 7; ++dj)
            s = fmaf(xw[iy + 2 - di][jx + 8 - dj], wp[di * 7 + dj], s);
        m = fmaxf(m, s);
      }
    }
    float v = fmaxf(m + b1[co], 0.f);
    a1[((b * 50 + co) * 32 + pr) * 64 + pc] = v;
  }
  // folded weight transpose.
  // w2t: i = ((ci*5+coc)*21+tap)*10+co  <-  w2[(coc*10+co)*1050 + ci*21 + tap]
  // w3t/w4t: old [ci][tap][co(50)] layout.
  if (blockIdx.y == 0) {
    int base = (blockIdx.z * 8 + blockIdx.x) * 256 + threadIdx.x;  // 0..65535
    for (int i = base; i < 90000; i += 65536) {
      if (i < 52500) {
        int co = i % 10; int t = i / 10;
        int tap = t % 21; t /= 21;
        int coc = t % 5;  int ci = t / 5;
        w2t[i] = w2[(coc * 10 + co) * 1050 + ci * 21 + tap];
        int co4 = i % 50, r4 = i / 50;
        w4t[i] = w4[co4 * 1050 + r4];
      } else {                  // w3: 50*50*3*5
        int j2 = i - 52500;
        int co = j2 % 50, r = j2 / 50;
        w3t[j2] = w3[co * 750 + r];
      }
    }
  }
}

// ---------------- K2: conv2 (50->50, 3x7 circular, 32x64) + maxpool 2x4 + relu -------
// r21: byte-exact r15 zero-barrier body (94 us verified); ONLY the weight addressing
// changes: per (ci, co-chunk) the 210 weight floats are one contiguous 840B packet
// (wci = w2t + (ci*5+cocB)*210, taps at stride 10). r20's version of this was
// MIS-INDEXED (2*cocB, 5-co packets) -> wrong data + 172us; this is the real test.
__global__ __launch_bounds__(256) void k2(const float* __restrict__ a1,
                                          const float* __restrict__ w2t,
                                          const float* __restrict__ b2,
                                          float* __restrict__ a2) {
  __shared__ float sm[2560];       // pool epilogue only: [co(10)][row(4)][col(64)]
  int b = blockIdx.z;
  int r0 = blockIdx.x * 4;         // pre-pool rows r0..r0+3
  int cocB = blockIdx.y;           // co chunk 0..4 (10 co)
  int co0 = cocB * 10;
  int y = threadIdx.x >> 6;        // 0..3 (wave id) -> pre-pool row r0+y
  int lane = threadIdx.x & 63;     // column
  int offA = ((r0 + y - 2) & 31) * 64 + lane;
  int offB = ((r0 + y - 1) & 31) * 64 + lane;
  int offC = ((r0 + y) & 31) * 64 + lane;
  int idx1 = (lane - 1) & 63, idx2 = (lane - 2) & 63, idx3 = (lane - 3) & 63;
  int idx4 = (lane - 4) & 63, idx5 = (lane - 5) & 63, idx6 = (lane - 6) & 63;
  float acc[10];
#pragma unroll
  for (int co = 0; co < 10; ++co) acc[co] = b2[co0 + co];
  const float* ain = a1 + b * (50 * 2048);
  float vA = ain[offA], vB = ain[offB], vC = ain[offC];
  for (int ci = 0; ci < 50; ++ci) {
    int cin = (ci + 1 < 50) ? (ci + 1) : 49;
    const float* np = ain + cin * 2048;
    float nA = np[offA], nB = np[offB], nC = np[offC];
    const float* wci = w2t + (ci * 5 + cocB) * 210;   // contiguous packet, uniform
#pragma unroll
    for (int di = 0; di < 3; ++di) {
      float v = (di == 0) ? vC : (di == 1) ? vB : vA;
      const float* wr = wci + di * 70;     // [tap7][co10], contiguous
      float x1 = __shfl(v, idx1, 64);
      float x2 = __shfl(v, idx2, 64);
      float x3 = __shfl(v, idx3, 64);
      float x4 = __shfl(v, idx4, 64);
      float x5 = __shfl(v, idx5, 64);
      float x6 = __shfl(v, idx6, 64);
#pragma unroll
      for (int co = 0; co < 10; ++co) acc[co] = fmaf(v,  wr[co], acc[co]);
#pragma unroll
      for (int co = 0; co < 10; ++co) acc[co] = fmaf(x1, wr[10 + co], acc[co]);
#pragma unroll
      for (int co = 0; co < 10; ++co) acc[co] = fmaf(x2, wr[20 + co], acc[co]);
#pragma unroll
      for (int co = 0; co < 10; ++co) acc[co] = fmaf(x3, wr[30 + co], acc[co]);
#pragma unroll
      for (int co = 0; co < 10; ++co) acc[co] = fmaf(x4, wr[40 + co], acc[co]);
#pragma unroll
      for (int co = 0; co < 10; ++co) acc[co] = fmaf(x5, wr[50 + co], acc[co]);
#pragma unroll
      for (int co = 0; co < 10; ++co) acc[co] = fmaf(x6, wr[60 + co], acc[co]);
    }
    vA = nA; vB = nB; vC = nC;
  }
  // pool 2x4 + relu through LDS (conflict-free)
#pragma unroll
  for (int k = 0; k < 10; ++k)
    sm[k * 256 + y * 64 + lane] = acc[k];
  __syncthreads();
  for (int w = threadIdx.x; w < 320; w += 256) {
    int cop = w / 32;
    int pr = (w >> 4) & 1;
    int pc = w & 15;
    float m = -1e30f;
#pragma unroll
    for (int yy = 0; yy < 2; ++yy)
#pragma unroll
      for (int xx = 0; xx < 4; ++xx)
        m = fmaxf(m, sm[cop * 256 + (pr * 2 + yy) * 64 + pc * 4 + xx]);
    m = fmaxf(m, 0.f);
    a2[((b * 50 + co0 + cop) * 16 + (r0 >> 1) + pr) * 16 + pc] = m;
  }
}

// ---------------- K3: combine(even + mean(odd)) -> upsample(2,4)-sparse conv3 (3x5) + relu
// r14 verified: co-chunk 5, grid (4,10,16)=640 blocks. r18: mean phase vectorized.
__global__ __launch_bounds__(512) void k3(const float* __restrict__ a2,
                                          const float* __restrict__ w3t,
                                          const float* __restrict__ b3,
                                          float* __restrict__ a3) {
  __shared__ float ts[4000];     // [ci(50)][rr(5)][tc(16)]
  __shared__ float mean_s[64];
  __shared__ float part[200];
  int b = blockIdx.z;
  int r0 = blockIdx.x * 8;       // output rows r0..r0+7
  int co0 = blockIdx.y * 5;      // co chunk of 5
  int tid = threadIdx.x;
  const float* aodd = a2 + (2 * b + 1) * (50 * 256);
  if (tid < 200) {
    int ci = tid >> 2, p = tid & 3;
    const float4* ap = (const float4*)(aodd + ci * 256 + p * 64);
    float s = 0.f;
#pragma unroll
    for (int k = 0; k < 16; ++k) {
      float4 t = ap[k];
      s += t.x; s += t.y; s += t.z; s += t.w;
    }
    part[tid] = s;
  }
  __syncthreads();
  if (tid < 50)
    mean_s[tid] = (part[4 * tid] + part[4 * tid + 1] + part[4 * tid + 2] + part[4 * tid + 3]) * (1.f / 256.f);
  __syncthreads();
  const float* aev = a2 + (2 * b) * (50 * 256);
  for (int e = tid; e < 4000; e += 512) {
    int ci = e / 80;
    int rr = (e >> 4) % 5;
    int tc = e & 15;
    int trow = ((r0 >> 1) - 1 + rr) & 15;
    ts[e] = aev[ci * 256 + trow * 16 + tc] + mean_s[ci];
  }
  __syncthreads();
  int wv = __builtin_amdgcn_readfirstlane(tid >> 6);   // 0..7, force SGPR
  int lane = tid & 63;
  int p = wv >> 2;               // row parity class
  int m = wv & 3;                // j%4 class
  int q = lane & 15;
  int yidx = lane >> 4;          // 0..3
  int i = r0 + 2 * yidx + p;
  int j = 4 * q + m;
  float acc[5];
#pragma unroll
  for (int co = 0; co < 5; ++co) acc[co] = b3[co0 + co];
  int ndi = (p == 0) ? 2 : 1;    // even rows: di in {0,2}; odd: {1}
  int ndj = (m == 0) ? 2 : 1;    // kw=5: m==0 -> dj in {0,4}; else {m}
  for (int aa = 0; aa < ndi; ++aa) {
    int di = (p == 0) ? (2 * aa) : 1;
    int rr = 1 + ((2 * yidx + p - di) >> 1);
    for (int e2 = 0; e2 < ndj; ++e2) {
      int dj = (m == 0) ? (4 * e2) : m;
      int tc = ((j - dj + 64) >> 2) & 15;
      for (int ci = 0; ci < 50; ++ci) {
        float xv = ts[ci * 80 + rr * 16 + tc];
        const float* wrow = w3t + (ci * 15 + di * 5 + dj) * 50 + co0;  // wave-uniform
#pragma unroll
        for (int co = 0; co < 5; ++co)
          acc[co] = fmaf(xv, wrow[co], acc[co]);
      }
    }
  }
  float* aout = a3 + b * (50 * 2048);
#pragma unroll
  for (int co = 0; co < 5; ++co)
    aout[(co0 + co) * 2048 + i * 64 + j] = fmaxf(acc[co], 0.f);
}

// ---------------- K4: upsample(2,4)-sparse conv4 (3x7, 64x256) + relu ----------------
// r10-verified LDS ratio-2 form. Rows r0+rowsel and r0+rowsel+2.
// grid (16,5,16)=1280 x 512 thr.
__global__ __launch_bounds__(512) void k4(const float* __restrict__ a3,
                                          const float* __restrict__ w4t,
                                          const float* __restrict__ b4,
                                          float* __restrict__ a4) {
  __shared__ __align__(16) float s4[9600];   // [ci(50)][rr(3)][col(64)]
  int b = blockIdx.z;
  int r0 = blockIdx.x * 4;       // output rows r0..r0+3
  int co0 = blockIdx.y * 10;
  int tid = threadIdx.x;
  const float* ain = a3 + b * (50 * 2048);
  int prb = (r0 >> 1) - 1;       // pooled-row base (rr=0)
  for (int e = tid; e < 2400; e += 512) {    // float4 granules [ci][rr(3)][c4(16)]
    int ci = e / 48;
    int rem = e - ci * 48;
    int rr = rem >> 4;
    int c4 = rem & 15;
    int row = (prb + rr) & 31;
    *(float4*)&s4[(ci * 3 + rr) * 64 + c4 * 4] =
        *(const float4*)&ain[ci * 2048 + row * 64 + c4 * 4];
  }
  __syncthreads();
  int wv = __builtin_amdgcn_readfirstlane(tid >> 6);  // 0..7
  int lane = tid & 63;
  int rowsel = wv >> 2;          // 0..1 (wave-uniform)
  int m = wv & 3;
  int j = 4 * lane + m;
  float acc[2][10];
#pragma unroll
  for (int co = 0; co < 10; ++co) {
    float bc = b4[co0 + co];
    acc[0][co] = bc; acc[1][co] = bc;
  }
  int ndi = (rowsel == 0) ? 2 : 1;
  int ndj = (m < 3) ? 2 : 1;     // kw=7: dj in {m, m+4} when m<3
  for (int aa = 0; aa < ndi; ++aa) {
    int di = (rowsel == 0) ? (2 * aa) : 1;
    int rrb = 1 + ((rowsel - di) >> 1);   // rr for the k=0 row; k=1 row uses rrb+1
    for (int e2 = 0; e2 < ndj; ++e2) {
      int dj = m + 4 * e2;
      int tc = ((j - dj) >> 2) & 63;      // j-dj is multiple of 4
      for (int ci = 0; ci < 50; ++ci) {
        float xv0 = s4[ci * 192 + rrb * 64 + tc];
        float xv1 = s4[ci * 192 + (rrb + 1) * 64 + tc];
        const float* wrow = w4t + (ci * 21 + di * 7 + dj) * 50 + co0;  // wave-uniform
#pragma unroll
        for (int co = 0; co < 10; ++co) {
          float w = wrow[co];
          acc[0][co] = fmaf(xv0, w, acc[0][co]);
          acc[1][co] = fmaf(xv1, w, acc[1][co]);
        }
      }
    }
  }
  float* aout = a4 + b * (50 * 16384);
  int i0 = r0 + rowsel, i1 = r0 + rowsel + 2;
#pragma unroll
  for (int co = 0; co < 10; ++co) {
    aout[(co0 + co) * 16384 + i0 * 256 + j] = fmaxf(acc[0][co], 0.f);
    aout[(co0 + co) * 16384 + i1 * 256 + j] = fmaxf(acc[1][co], 0.f);
  }
}

// ---------------- K5: conv5 (50->1, 3x7 circular, 64x256) + sigmoid ------------------
// r18-verified: 8-row blocks (512 thr), 512 blocks; float4 staging; w5 in LDS.
__global__ __launch_bounds__(512) void k5(const float* __restrict__ a4,
                                          const float* __restrict__ w5,
                                          const float* __restrict__ b5,
                                          float* __restrict__ out) {
  __shared__ __align__(16) float s5[4000];   // [ci(5)][rr(10)][c(80)], c-8 = col - jb
  __shared__ float smw5[1056];
  int bid = blockIdx.x;          // 512 blocks
  int b = bid >> 5;              // img 0..15
  int rem = bid & 31;
  int r0 = (rem >> 2) * 8;       // output rows r0..r0+7
  int jb = (rem & 3) * 64;       // col quarter base
  int tid = threadIdx.x;
  int y = tid >> 6;              // row 0..7
  int q = tid & 63;              // col within quarter
  for (int e = tid; e < 1050; e += 512) smw5[e] = w5[e];
  float acc = b5[0];
  const float* ain = a4 + b * (50 * 16384);
  for (int cc = 0; cc < 10; ++cc) {          // ci chunks of 5
    __syncthreads();
    for (int e = tid; e < 1000; e += 512) {  // float4 granules [ci(5)][rr(10)][g(20)]
      int ci = e / 200;
      int rem2 = e - ci * 200;
      int rr = rem2 / 20;
      int g = rem2 - rr * 20;
      int row = (r0 - 2 + rr) & 63;
      int col = (jb + 4 * g - 8) & 255;      // 4-aligned, wraps cleanly
      *(float4*)&s5[(ci * 10 + rr) * 80 + 4 * g] =
          *(const float4*)&ain[(cc * 5 + ci) * 16384 + row * 256 + col];
    }
    __syncthreads();
#pragma unroll
    for (int ci = 0; ci < 5; ++ci) {
#pragma unroll
      for (int di = 0; di < 3; ++di) {
        const float* base = s5 + ci * 800 + (y + 2 - di) * 80 + 8 + q;
        const float* wp = smw5 + ((cc * 5 + ci) * 3 + di) * 7;   // uniform LDS
#pragma unroll
        for (int dj = 0; dj < 7; ++dj)
          acc = fmaf(base[-dj], wp[dj], acc);
      }
    }
  }
  out[b * 16384 + (r0 + y) * 256 + jb + q] = 1.f / (1.f + expf(-acc));
}

extern "C" void kernel_launch(void* const* d_in, const int* in_sizes, int n_in,
                              void* d_out, int out_size, void* d_ws, size_t ws_size,
                              hipStream_t stream) {
  (void)in_sizes; (void)n_in; (void)out_size; (void)ws_size;
  const float* x  = (const float*)d_in[0];
  const float* w1 = (const float*)d_in[1];
  const float* b1 = (const float*)d_in[2];
  const float* w2 = (const float*)d_in[3];
  const float* b2 = (const float*)d_in[4];
  const float* w3 = (const float*)d_in[5];
  const float* b3 = (const float*)d_in[6];
  const float* w4 = (const float*)d_in[7];
  const float* b4 = (const float*)d_in[8];
  const float* w5 = (const float*)d_in[9];
  const float* b5 = (const float*)d_in[10];
  float* out = (float*)d_out;
  float* ws  = (float*)d_ws;
  float* w2t = ws;                       // 52500 (k2 packet layout)
  float* w3t = w2t + 52500;              // 37500
  float* w4t = w3t + 37500;              // 52500
  float* a1  = w4t + 52500;              // 32*50*32*64  = 3,276,800
  float* a2  = a1 + 32 * 50 * 32 * 64;   // 32*50*16*16  = 409,600
  float* a3  = a2 + 32 * 50 * 16 * 16;   // 16*50*32*64  = 1,638,400
  float* a4  = a3 + 16 * 50 * 32 * 64;   // 16*50*64*256 = 13,107,200
  hipLaunchKernelGGL(k1, dim3(8, 5, 32), dim3(256), 0, stream, x, w1, b1, a1,
                     w2, w3, w4, w2t, w3t, w4t);
  hipLaunchKernelGGL(k2, dim3(8, 5, 32), dim3(256), 0, stream, a1, w2t, b2, a2);
  hipLaunchKernelGGL(k3, dim3(4, 10, 16), dim3(512), 0, stream, a2, w3t, b3, a3);
  hipLaunchKernelGGL(k4, dim3(16, 5, 16), dim3(512), 0, stream, a3, w4t, b4, a4);
  hipLaunchKernelGGL(k5, dim3(512), dim3(512), 0, stream, a4, w5, b5, out);
}